// Round 11
// baseline (242.903 us; speedup 1.0000x reference)
//
#include <hip/hip_runtime.h>
#include <hip/hip_bf16.h>
#include <math.h>

#define NB 10000      // nodes
#define BB 4          // batch
#define EE 160000     // edges
#define MM (NB * BB)  // 40000 GEMM rows, ordered (B,N)
#define SLOTS 64      // max degree (Poisson(16); P(>=64) ~ 1e-18, guarded)

typedef __attribute__((ext_vector_type(8))) short short8;
typedef __attribute__((ext_vector_type(4))) float floatx4;

// ---------------- helpers ----------------

__device__ inline unsigned pk(float a, float b) {
  __hip_bfloat16 ha = __float2bfloat16(a), hb = __float2bfloat16(b);
  unsigned short ua = *(unsigned short*)&ha, ub = *(unsigned short*)&hb;
  return (unsigned)ua | ((unsigned)ub << 16);
}

__device__ inline float bf2f(ushort u) {
  unsigned v = (unsigned)u << 16;
  return __uint_as_float(v);
}

__device__ inline ushort f2bf(float f) {
  __hip_bfloat16 h = __float2bfloat16(f);
  return *(unsigned short*)&h;
}

__device__ inline void fma8(float* a, uint4 v, float k) {
  a[0] += k * __uint_as_float(v.x << 16);
  a[1] += k * __uint_as_float(v.x & 0xffff0000u);
  a[2] += k * __uint_as_float(v.y << 16);
  a[3] += k * __uint_as_float(v.y & 0xffff0000u);
  a[4] += k * __uint_as_float(v.z << 16);
  a[5] += k * __uint_as_float(v.z & 0xffff0000u);
  a[6] += k * __uint_as_float(v.w << 16);
  a[7] += k * __uint_as_float(v.w & 0xffff0000u);
}

// ---------------- fused misc: edge fill + build_xru + fragment-major W pack -------
// blocks [0,625): bucket fill; [625,3125): build_xru;
// [3125,3149): Wru pack; [3149,3155): Wc in-half pack; [3155,3161): Wc rh-half.

__global__ __launch_bounds__(256) void k_misc(
    const int* __restrict__ src, const int* __restrict__ dst,
    const float* __restrict__ ker, int* __restrict__ cnt,
    uint2* __restrict__ edges,
    const float* __restrict__ in, const float* __restrict__ hx,
    ushort* __restrict__ x,
    const float* __restrict__ Wru, const float* __restrict__ Wc,
    ushort* __restrict__ Bru, ushort* __restrict__ Bcin,
    ushort* __restrict__ Bc2) {
  int blk = blockIdx.x;
  if (blk < 625) {
    int e = blk * 256 + threadIdx.x;
    if (e < EE) {
      int n = dst[e];
      int slot = atomicAdd(&cnt[n], 1);
      if (slot < SLOTS)
        edges[(size_t)n * SLOTS + slot] =
            make_uint2((unsigned)src[e], __float_as_uint(ker[e]));
    }
  } else if (blk < 3125) {
    int tid = (blk - 625) * 256 + threadIdx.x;  // [0, MM*16)
    int m = tid >> 4;
    int c8 = (tid & 15) << 3;
    const float* sp = (c8 < 64) ? (in + (size_t)m * 64 + c8)
                                : (hx + (size_t)m * 64 + (c8 - 64));
    float4 f0 = *(const float4*)(sp);
    float4 f1 = *(const float4*)(sp + 4);
    uint4 o;
    o.x = pk(f0.x, f0.y); o.y = pk(f0.z, f0.w);
    o.z = pk(f1.x, f1.y); o.w = pk(f1.z, f1.w);
    *(uint4*)(x + (size_t)m * 128 + c8) = o;
  } else if (blk < 3149) {
    int t = (blk - 3125) * 256 + threadIdx.x;   // [0, 6144)
    int kt = t >> 9;
    int nt = (t >> 6) & 7;
    int lane = t & 63;
    int quad = lane >> 4, lr = lane & 15;
    int colb = nt * 16 + lr;
    int kb = kt * 32 + quad * 8;
    short8 v;
#pragma unroll
    for (int j = 0; j < 8; ++j) v[j] = (short)f2bf(Wru[(size_t)(kb + j) * 128 + colb]);
    *(short8*)(Bru + (size_t)t * 8) = v;
  } else if (blk < 3155) {
    int t = (blk - 3149) * 256 + threadIdx.x;   // [0, 1536)
    int ktc = t >> 8;
    int nt = (t >> 6) & 3;
    int lane = t & 63;
    int quad = lane >> 4, lr = lane & 15;
    int vv = ktc >> 1, h = ktc & 1;
    int colb = nt * 16 + lr;
    int kb = vv * 128 + h * 32 + quad * 8;      // in-half rows of Wc
    short8 v;
#pragma unroll
    for (int j = 0; j < 8; ++j) v[j] = (short)f2bf(Wc[(size_t)(kb + j) * 64 + colb]);
    *(short8*)(Bcin + (size_t)t * 8) = v;
  } else {
    int t = (blk - 3155) * 256 + threadIdx.x;   // [0, 1536)
    int ktc = t >> 8;
    int nt = (t >> 6) & 3;
    int lane = t & 63;
    int quad = lane >> 4, lr = lane & 15;
    int vv = ktc >> 1, h = ktc & 1;
    int colb = nt * 16 + lr;
    int kb = vv * 128 + 64 + h * 32 + quad * 8; // rh-half rows of Wc
    short8 v;
#pragma unroll
    for (int j = 0; j < 8; ++j) v[j] = (short)f2bf(Wc[(size_t)(kb + j) * 64 + colb]);
    *(short8*)(Bc2 + (size_t)t * 8) = v;
  }
}

// ---------------- per-batch 128ch hop: slice (2.56MB) L2-resident by construction -
// Grid 2500 x 4 waves; wave = one node's 256B row; 4 edge groups x 16 lanes.

__global__ __launch_bounds__(256) void k_prop128(const ushort* __restrict__ xb,
                                                 ushort* __restrict__ yb,
                                                 const int* __restrict__ cnt,
                                                 const uint2* __restrict__ edges) {
  int w = threadIdx.x >> 6;
  int lane = threadIdx.x & 63;
  int n = blockIdx.x * 4 + w;
  int g = lane >> 4;                                // edge group 0..3
  int o8 = (lane & 15) << 3;                        // 8 bf16 per lane
  const uint2* ebase = edges + (size_t)n * SLOTS;
  int deg = min(cnt[n], SLOTS);
  float acc[8];
#pragma unroll
  for (int j = 0; j < 8; ++j) acc[j] = 0.f;
  int i = g;
  for (; i + 12 < deg; i += 16) {                   // 4 edges of this group in flight
    uint2 e0 = ebase[i], e1 = ebase[i + 4], e2 = ebase[i + 8], e3 = ebase[i + 12];
    uint4 v0 = *(const uint4*)(xb + (size_t)e0.x * 128 + o8);
    uint4 v1 = *(const uint4*)(xb + (size_t)e1.x * 128 + o8);
    uint4 v2 = *(const uint4*)(xb + (size_t)e2.x * 128 + o8);
    uint4 v3 = *(const uint4*)(xb + (size_t)e3.x * 128 + o8);
    fma8(acc, v0, __uint_as_float(e0.y));
    fma8(acc, v1, __uint_as_float(e1.y));
    fma8(acc, v2, __uint_as_float(e2.y));
    fma8(acc, v3, __uint_as_float(e3.y));
  }
  for (; i < deg; i += 4) {
    uint2 e0 = ebase[i];
    uint4 v0 = *(const uint4*)(xb + (size_t)e0.x * 128 + o8);
    fma8(acc, v0, __uint_as_float(e0.y));
  }
#pragma unroll
  for (int j = 0; j < 8; ++j) {
    acc[j] += __shfl_xor(acc[j], 16);
    acc[j] += __shfl_xor(acc[j], 32);
  }
  if (g == 0) {
    uint4 o;
    o.x = pk(acc[0], acc[1]); o.y = pk(acc[2], acc[3]);
    o.z = pk(acc[4], acc[5]); o.w = pk(acc[6], acc[7]);
    *(uint4*)(yb + (size_t)n * 128 + o8) = o;
  }
}

// ---------------- per-batch 64ch hop: slice (1.28MB) L2-resident ------------------
// Grid 2500 x 4 waves; wave = one node's 128B row; 8 edge groups x 8 lanes.

__global__ __launch_bounds__(256) void k_prop64(const ushort* __restrict__ xb,
                                                ushort* __restrict__ yb,
                                                const int* __restrict__ cnt,
                                                const uint2* __restrict__ edges) {
  int w = threadIdx.x >> 6;
  int lane = threadIdx.x & 63;
  int n = blockIdx.x * 4 + w;
  int g = lane >> 3;                                // edge group 0..7
  int o8 = (lane & 7) << 3;
  const uint2* ebase = edges + (size_t)n * SLOTS;
  int deg = min(cnt[n], SLOTS);
  float acc[8];
#pragma unroll
  for (int j = 0; j < 8; ++j) acc[j] = 0.f;
  int i = g;
  for (; i + 8 < deg; i += 16) {
    uint2 e0 = ebase[i], e1 = ebase[i + 8];
    uint4 v0 = *(const uint4*)(xb + (size_t)e0.x * 64 + o8);
    uint4 v1 = *(const uint4*)(xb + (size_t)e1.x * 64 + o8);
    fma8(acc, v0, __uint_as_float(e0.y));
    fma8(acc, v1, __uint_as_float(e1.y));
  }
  for (; i < deg; i += 8) {
    uint2 e0 = ebase[i];
    uint4 v0 = *(const uint4*)(xb + (size_t)e0.x * 64 + o8);
    fma8(acc, v0, __uint_as_float(e0.y));
  }
#pragma unroll
  for (int j = 0; j < 8; ++j) {
    acc[j] += __shfl_xor(acc[j], 8);
    acc[j] += __shfl_xor(acc[j], 16);
    acc[j] += __shfl_xor(acc[j], 32);
  }
  if (g == 0) {
    uint4 o;
    o.x = pk(acc[0], acc[1]); o.y = pk(acc[2], acc[3]);
    o.z = pk(acc[4], acc[5]); o.w = pk(acc[6], acc[7]);
    *(uint4*)(yb + (size_t)n * 64 + o8) = o;
  }
}

// ---------------- GEMM1: ru (K=384,N=128) + fused c-in-partial (K=192,N=64) -------
// Grid 625 x 4 waves; wave = 16 rows x all cols. A frags hoisted (12);
// packed-B double-buffered: every B load is 64 lanes x 16B contiguous (1KB).

__global__ __launch_bounds__(256) void k_gemm1(
    const ushort* __restrict__ x, const ushort* __restrict__ y1,
    const ushort* __restrict__ y2, const ushort* __restrict__ Bru,
    const ushort* __restrict__ Bcin, const float* __restrict__ bias,
    const float* __restrict__ hx, ushort* __restrict__ rh0,
    ushort* __restrict__ u, ushort* __restrict__ cp) {
  const int tid = threadIdx.x;
  const int lane = tid & 63;
  const int w = tid >> 6;
  const int m0 = blockIdx.x * 64 + w * 16;
  const int lr = lane & 15;
  const int quad = lane >> 4;
  const int koff = quad * 8;

  const ushort* vb[3] = {x, y1, y2};
  short8 a[12];
#pragma unroll
  for (int v = 0; v < 3; ++v)
#pragma unroll
    for (int h = 0; h < 4; ++h)
      a[v * 4 + h] = *(const short8*)(vb[v] + (size_t)(m0 + lr) * 128 + h * 32 + koff);

  const ushort* bru = Bru + (size_t)lane * 8;
  const ushort* bcin = Bcin + (size_t)lane * 8;

  floatx4 aru[8], ac[4];
#pragma unroll
  for (int nt = 0; nt < 8; ++nt) aru[nt] = {0.f, 0.f, 0.f, 0.f};
#pragma unroll
  for (int nt = 0; nt < 4; ++nt) ac[nt] = {0.f, 0.f, 0.f, 0.f};

  short8 bc[8];
#pragma unroll
  for (int nt = 0; nt < 8; ++nt) bc[nt] = *(const short8*)(bru + (size_t)nt * 512);

#pragma unroll
  for (int kt = 0; kt < 12; ++kt) {
    short8 bn[8];
    if (kt < 11) {
#pragma unroll
      for (int nt = 0; nt < 8; ++nt)
        bn[nt] = *(const short8*)(bru + (size_t)((kt + 1) * 8 + nt) * 512);
    }
#pragma unroll
    for (int nt = 0; nt < 8; ++nt)
      aru[nt] = __builtin_amdgcn_mfma_f32_16x16x32_bf16(a[kt], bc[nt], aru[nt], 0, 0, 0);
    const int h = kt & 3;
    if (h < 2) {
      const int ktc = (kt >> 2) * 2 + h;
#pragma unroll
      for (int nt = 0; nt < 4; ++nt) {
        short8 b2 = *(const short8*)(bcin + (size_t)(ktc * 4 + nt) * 512);
        ac[nt] = __builtin_amdgcn_mfma_f32_16x16x32_bf16(a[kt], b2, ac[nt], 0, 0, 0);
      }
    }
    if (kt < 11) {
#pragma unroll
      for (int nt = 0; nt < 8; ++nt) bc[nt] = bn[nt];
    }
  }

#pragma unroll
  for (int nt = 0; nt < 8; ++nt) {
    int col = nt * 16 + lr;
    float bv = bias[col];
#pragma unroll
    for (int i = 0; i < 4; ++i) {
      int m = m0 + quad * 4 + i;
      float s = 1.f / (1.f + expf(-(aru[nt][i] + bv)));
      if (nt < 4) {
        rh0[(size_t)m * 64 + col] = f2bf(s * hx[(size_t)m * 64 + col]);
      } else {
        u[(size_t)m * 64 + (col - 64)] = f2bf(s);
      }
    }
  }
#pragma unroll
  for (int nt = 0; nt < 4; ++nt) {
    int col = nt * 16 + lr;
#pragma unroll
    for (int i = 0; i < 4; ++i) {
      int m = m0 + quad * 4 + i;
      cp[(size_t)m * 64 + col] = f2bf(ac[nt][i]);
    }
  }
}

// ---------------- GEMM2: c-rh (K=192 over rh0/1/2) + cp + GRU output --------------

__global__ __launch_bounds__(256) void k_gemm2(
    const ushort* __restrict__ rh0, const ushort* __restrict__ rh1,
    const ushort* __restrict__ rh2, const ushort* __restrict__ Bc2,
    const float* __restrict__ bias, const ushort* __restrict__ cp,
    const ushort* __restrict__ uu, const float* __restrict__ hx,
    float* __restrict__ out) {
  const int tid = threadIdx.x;
  const int lane = tid & 63;
  const int w = tid >> 6;
  const int m0 = blockIdx.x * 64 + w * 16;
  const int lr = lane & 15;
  const int quad = lane >> 4;
  const int koff = quad * 8;

  const ushort* vb[3] = {rh0, rh1, rh2};
  short8 a[6];
#pragma unroll
  for (int v = 0; v < 3; ++v)
#pragma unroll
    for (int h = 0; h < 2; ++h)
      a[v * 2 + h] = *(const short8*)(vb[v] + (size_t)(m0 + lr) * 64 + h * 32 + koff);

  float cpv[16], uv[16], hxv[16];
#pragma unroll
  for (int nt = 0; nt < 4; ++nt)
#pragma unroll
    for (int i = 0; i < 4; ++i) {
      size_t idx = (size_t)(m0 + quad * 4 + i) * 64 + nt * 16 + lr;
      cpv[nt * 4 + i] = bf2f(cp[idx]);
      uv[nt * 4 + i] = bf2f(uu[idx]);
      hxv[nt * 4 + i] = hx[idx];
    }

  const ushort* bp = Bc2 + (size_t)lane * 8;
  floatx4 acc[4];
#pragma unroll
  for (int nt = 0; nt < 4; ++nt) acc[nt] = {0.f, 0.f, 0.f, 0.f};

  short8 bc[4];
#pragma unroll
  for (int nt = 0; nt < 4; ++nt) bc[nt] = *(const short8*)(bp + (size_t)nt * 512);

#pragma unroll
  for (int kt = 0; kt < 6; ++kt) {
    short8 bn[4];
    if (kt < 5) {
#pragma unroll
      for (int nt = 0; nt < 4; ++nt)
        bn[nt] = *(const short8*)(bp + (size_t)((kt + 1) * 4 + nt) * 512);
    }
#pragma unroll
    for (int nt = 0; nt < 4; ++nt)
      acc[nt] = __builtin_amdgcn_mfma_f32_16x16x32_bf16(a[kt], bc[nt], acc[nt], 0, 0, 0);
    if (kt < 5) {
#pragma unroll
      for (int nt = 0; nt < 4; ++nt) bc[nt] = bn[nt];
    }
  }

#pragma unroll
  for (int nt = 0; nt < 4; ++nt) {
    int col = nt * 16 + lr;
    float bv = bias[col];
#pragma unroll
    for (int i = 0; i < 4; ++i) {
      int m = m0 + quad * 4 + i;
      int j = nt * 4 + i;
      float c = tanhf(acc[nt][i] + cpv[j] + bv);
      out[(size_t)m * 64 + col] = uv[j] * hxv[j] + (1.f - uv[j]) * c;
    }
  }
}

// ---------------- launch ----------------

extern "C" void kernel_launch(void* const* d_in, const int* in_sizes, int n_in,
                              void* d_out, int out_size, void* d_ws, size_t ws_size,
                              hipStream_t stream) {
  const float* d_inputs = (const float*)d_in[0];
  const float* d_hx     = (const float*)d_in[1];
  const int*   d_sidx   = (const int*)d_in[2];
  const float* d_ker    = (const float*)d_in[3];
  const float* d_Wru    = (const float*)d_in[4];
  const float* d_bru    = (const float*)d_in[5];
  const float* d_Wc     = (const float*)d_in[6];
  const float* d_bc     = (const float*)d_in[7];
  float* out = (float*)d_out;
  const int* src = d_sidx;
  const int* dst = d_sidx + EE;

  // workspace layout (16B-aligned chunks); all tensors (B,N,C)
  ushort* x     = (ushort*)d_ws;                    // MM*128 [in|hx]
  ushort* y1    = x + (size_t)MM * 128;             // A [in|hx]
  ushort* y2    = y1 + (size_t)MM * 128;            // A^2 [in|hx]
  ushort* rh0   = y2 + (size_t)MM * 128;            // MM*64 r*hx
  ushort* rh1   = rh0 + (size_t)MM * 64;
  ushort* rh2   = rh1 + (size_t)MM * 64;
  ushort* u     = rh2 + (size_t)MM * 64;            // MM*64 bf16 u gate
  ushort* cp    = u + (size_t)MM * 64;              // MM*64 bf16 c-in-partial
  ushort* Bru   = cp + (size_t)MM * 64;             // packed 12*8*64*8
  ushort* Bcin  = Bru + 12 * 8 * 64 * 8;            // packed 6*4*64*8
  ushort* Bc2   = Bcin + 6 * 4 * 64 * 8;            // packed 6*4*64*8
  uint2*  edges = (uint2*)(Bc2 + 6 * 4 * 64 * 8);   // NB*SLOTS
  int*    cnt   = (int*)(edges + (size_t)NB * SLOTS);

  // cnt zero + fused {edge fill, build_xru, fragment-major W pack}
  hipMemsetAsync(cnt, 0, NB * sizeof(int), stream);
  k_misc<<<3161, 256, 0, stream>>>(src, dst, d_ker, cnt, edges,
                                   d_inputs, d_hx, x, d_Wru, d_Wc,
                                   Bru, Bcin, Bc2);

  // conv 1: per-batch two-hop propagation (slice L2-resident by construction)
  for (int b = 0; b < BB; ++b) {
    size_t o = (size_t)b * NB * 128;
    k_prop128<<<2500, 256, 0, stream>>>(x + o, y1 + o, cnt, edges);
    k_prop128<<<2500, 256, 0, stream>>>(y1 + o, y2 + o, cnt, edges);
  }
  k_gemm1<<<625, 256, 0, stream>>>(x, y1, y2, Bru, Bcin, d_bru, d_hx,
                                   rh0, u, cp);

  // conv 2: per-batch two-hop 64ch propagation
  for (int b = 0; b < BB; ++b) {
    size_t o = (size_t)b * NB * 64;
    k_prop64<<<2500, 256, 0, stream>>>(rh0 + o, rh1 + o, cnt, edges);
    k_prop64<<<2500, 256, 0, stream>>>(rh1 + o, rh2 + o, cnt, edges);
  }
  k_gemm2<<<625, 256, 0, stream>>>(rh0, rh1, rh2, Bc2, d_bc, cp, u, d_hx, out);
}

// Round 12
// 197.298 us; speedup vs baseline: 1.2311x; 1.2311x over previous
//
#include <hip/hip_runtime.h>
#include <hip/hip_bf16.h>
#include <math.h>

#define NB 10000      // nodes
#define BB 4          // batch
#define EE 160000     // edges
#define MM (NB * BB)  // 40000 GEMM rows, ordered (B,N)
#define SLOTS 64      // max degree (Poisson(16); P(>=64) ~ 1e-18, guarded)

typedef __attribute__((ext_vector_type(8))) short short8;
typedef __attribute__((ext_vector_type(4))) float floatx4;

// ---------------- helpers ----------------

__device__ inline unsigned pk(float a, float b) {
  __hip_bfloat16 ha = __float2bfloat16(a), hb = __float2bfloat16(b);
  unsigned short ua = *(unsigned short*)&ha, ub = *(unsigned short*)&hb;
  return (unsigned)ua | ((unsigned)ub << 16);
}

__device__ inline float bf2f(ushort u) {
  unsigned v = (unsigned)u << 16;
  return __uint_as_float(v);
}

__device__ inline ushort f2bf(float f) {
  __hip_bfloat16 h = __float2bfloat16(f);
  return *(unsigned short*)&h;
}

__device__ inline void fma8(float* a, uint4 v, float k) {
  a[0] += k * __uint_as_float(v.x << 16);
  a[1] += k * __uint_as_float(v.x & 0xffff0000u);
  a[2] += k * __uint_as_float(v.y << 16);
  a[3] += k * __uint_as_float(v.y & 0xffff0000u);
  a[4] += k * __uint_as_float(v.z << 16);
  a[5] += k * __uint_as_float(v.z & 0xffff0000u);
  a[6] += k * __uint_as_float(v.w << 16);
  a[7] += k * __uint_as_float(v.w & 0xffff0000u);
}

// ---------------- fused misc: edge fill + build_xru + fragment-major W pack -------
// blocks [0,625): bucket fill; [625,3125): build_xru;
// [3125,3149): Wru pack; [3149,3155): Wc in-half pack; [3155,3161): Wc rh-half.

__global__ __launch_bounds__(256) void k_misc(
    const int* __restrict__ src, const int* __restrict__ dst,
    const float* __restrict__ ker, int* __restrict__ cnt,
    uint2* __restrict__ edges,
    const float* __restrict__ in, const float* __restrict__ hx,
    ushort* __restrict__ x,
    const float* __restrict__ Wru, const float* __restrict__ Wc,
    ushort* __restrict__ Bru, ushort* __restrict__ Bcin,
    ushort* __restrict__ Bc2) {
  int blk = blockIdx.x;
  if (blk < 625) {
    int e = blk * 256 + threadIdx.x;
    if (e < EE) {
      int n = dst[e];
      int slot = atomicAdd(&cnt[n], 1);
      if (slot < SLOTS)
        edges[(size_t)n * SLOTS + slot] =
            make_uint2((unsigned)src[e], __float_as_uint(ker[e]));
    }
  } else if (blk < 3125) {
    int tid = (blk - 625) * 256 + threadIdx.x;  // [0, MM*16)
    int m = tid >> 4;
    int c8 = (tid & 15) << 3;
    const float* sp = (c8 < 64) ? (in + (size_t)m * 64 + c8)
                                : (hx + (size_t)m * 64 + (c8 - 64));
    float4 f0 = *(const float4*)(sp);
    float4 f1 = *(const float4*)(sp + 4);
    uint4 o;
    o.x = pk(f0.x, f0.y); o.y = pk(f0.z, f0.w);
    o.z = pk(f1.x, f1.y); o.w = pk(f1.z, f1.w);
    *(uint4*)(x + (size_t)m * 128 + c8) = o;
  } else if (blk < 3149) {
    int t = (blk - 3125) * 256 + threadIdx.x;   // [0, 6144)
    int kt = t >> 9;
    int nt = (t >> 6) & 7;
    int lane = t & 63;
    int quad = lane >> 4, lr = lane & 15;
    int colb = nt * 16 + lr;
    int kb = kt * 32 + quad * 8;
    short8 v;
#pragma unroll
    for (int j = 0; j < 8; ++j) v[j] = (short)f2bf(Wru[(size_t)(kb + j) * 128 + colb]);
    *(short8*)(Bru + (size_t)t * 8) = v;
  } else if (blk < 3155) {
    int t = (blk - 3149) * 256 + threadIdx.x;   // [0, 1536)
    int ktc = t >> 8;
    int nt = (t >> 6) & 3;
    int lane = t & 63;
    int quad = lane >> 4, lr = lane & 15;
    int vv = ktc >> 1, h = ktc & 1;
    int colb = nt * 16 + lr;
    int kb = vv * 128 + h * 32 + quad * 8;      // in-half rows of Wc
    short8 v;
#pragma unroll
    for (int j = 0; j < 8; ++j) v[j] = (short)f2bf(Wc[(size_t)(kb + j) * 64 + colb]);
    *(short8*)(Bcin + (size_t)t * 8) = v;
  } else {
    int t = (blk - 3155) * 256 + threadIdx.x;   // [0, 1536)
    int ktc = t >> 8;
    int nt = (t >> 6) & 3;
    int lane = t & 63;
    int quad = lane >> 4, lr = lane & 15;
    int vv = ktc >> 1, h = ktc & 1;
    int colb = nt * 16 + lr;
    int kb = vv * 128 + 64 + h * 32 + quad * 8; // rh-half rows of Wc
    short8 v;
#pragma unroll
    for (int j = 0; j < 8; ++j) v[j] = (short)f2bf(Wc[(size_t)(kb + j) * 64 + colb]);
    *(short8*)(Bc2 + (size_t)t * 8) = v;
  }
}

// ---------------- sparse hops, (B,N,C) layout (R7 configuration) ------------------
// Grid 10000 x 4 waves; wave = one (b,n) 256B row; 4 edge groups x 16 lanes.

__global__ __launch_bounds__(256) void k_prop128(const ushort* __restrict__ x,
                                                 ushort* __restrict__ y,
                                                 const int* __restrict__ cnt,
                                                 const uint2* __restrict__ edges) {
  int blk = blockIdx.x;
  int b = (blk & 7) >> 1;
  int jb = ((blk >> 3) << 1) | (blk & 1);          // 0..2499 within batch
  int w = threadIdx.x >> 6;
  int lane = threadIdx.x & 63;
  int n = jb * 4 + w;
  int g = lane >> 4;                                // edge group 0..3
  int o8 = (lane & 15) << 3;                        // 8 bf16 per lane
  const ushort* xb = x + (size_t)b * NB * 128;
  const uint2* ebase = edges + (size_t)n * SLOTS;
  int deg = min(cnt[n], SLOTS);
  float acc[8];
#pragma unroll
  for (int j = 0; j < 8; ++j) acc[j] = 0.f;
  int i = g;
  for (; i + 12 < deg; i += 16) {                   // 4 edges of this group in flight
    uint2 e0 = ebase[i], e1 = ebase[i + 4], e2 = ebase[i + 8], e3 = ebase[i + 12];
    uint4 v0 = *(const uint4*)(xb + (size_t)e0.x * 128 + o8);
    uint4 v1 = *(const uint4*)(xb + (size_t)e1.x * 128 + o8);
    uint4 v2 = *(const uint4*)(xb + (size_t)e2.x * 128 + o8);
    uint4 v3 = *(const uint4*)(xb + (size_t)e3.x * 128 + o8);
    fma8(acc, v0, __uint_as_float(e0.y));
    fma8(acc, v1, __uint_as_float(e1.y));
    fma8(acc, v2, __uint_as_float(e2.y));
    fma8(acc, v3, __uint_as_float(e3.y));
  }
  for (; i < deg; i += 4) {
    uint2 e0 = ebase[i];
    uint4 v0 = *(const uint4*)(xb + (size_t)e0.x * 128 + o8);
    fma8(acc, v0, __uint_as_float(e0.y));
  }
#pragma unroll
  for (int j = 0; j < 8; ++j) {
    acc[j] += __shfl_xor(acc[j], 16);
    acc[j] += __shfl_xor(acc[j], 32);
  }
  if (g == 0) {
    uint4 o;
    o.x = pk(acc[0], acc[1]); o.y = pk(acc[2], acc[3]);
    o.z = pk(acc[4], acc[5]); o.w = pk(acc[6], acc[7]);
    *(uint4*)(y + (size_t)b * NB * 128 + (size_t)n * 128 + o8) = o;
  }
}

__global__ __launch_bounds__(256) void k_prop64(const ushort* __restrict__ x,
                                                ushort* __restrict__ y,
                                                const int* __restrict__ cnt,
                                                const uint2* __restrict__ edges) {
  int blk = blockIdx.x;
  int b = (blk & 7) >> 1;
  int jb = ((blk >> 3) << 1) | (blk & 1);
  int w = threadIdx.x >> 6;
  int lane = threadIdx.x & 63;
  int n = jb * 4 + w;
  int g = lane >> 3;                                // edge group 0..7
  int o8 = (lane & 7) << 3;
  const ushort* xb = x + (size_t)b * NB * 64;
  const uint2* ebase = edges + (size_t)n * SLOTS;
  int deg = min(cnt[n], SLOTS);
  float acc[8];
#pragma unroll
  for (int j = 0; j < 8; ++j) acc[j] = 0.f;
  int i = g;
  for (; i + 8 < deg; i += 16) {
    uint2 e0 = ebase[i], e1 = ebase[i + 8];
    uint4 v0 = *(const uint4*)(xb + (size_t)e0.x * 64 + o8);
    uint4 v1 = *(const uint4*)(xb + (size_t)e1.x * 64 + o8);
    fma8(acc, v0, __uint_as_float(e0.y));
    fma8(acc, v1, __uint_as_float(e1.y));
  }
  for (; i < deg; i += 8) {
    uint2 e0 = ebase[i];
    uint4 v0 = *(const uint4*)(xb + (size_t)e0.x * 64 + o8);
    fma8(acc, v0, __uint_as_float(e0.y));
  }
#pragma unroll
  for (int j = 0; j < 8; ++j) {
    acc[j] += __shfl_xor(acc[j], 8);
    acc[j] += __shfl_xor(acc[j], 16);
    acc[j] += __shfl_xor(acc[j], 32);
  }
  if (g == 0) {
    uint4 o;
    o.x = pk(acc[0], acc[1]); o.y = pk(acc[2], acc[3]);
    o.z = pk(acc[4], acc[5]); o.w = pk(acc[6], acc[7]);
    *(uint4*)(y + (size_t)b * NB * 64 + (size_t)n * 64 + o8) = o;
  }
}

// ---------------- GEMM1: ru (K=384,N=128) + fused c-in-partial (K=192,N=64) -------
// Grid 625 x 4 waves; wave = 16 rows x all cols. A frags hoisted (12);
// packed-B double-buffered: every B load is 64 lanes x 16B contiguous (1KB).

__global__ __launch_bounds__(256) void k_gemm1(
    const ushort* __restrict__ x, const ushort* __restrict__ y1,
    const ushort* __restrict__ y2, const ushort* __restrict__ Bru,
    const ushort* __restrict__ Bcin, const float* __restrict__ bias,
    const float* __restrict__ hx, ushort* __restrict__ rh0,
    ushort* __restrict__ u, ushort* __restrict__ cp) {
  const int tid = threadIdx.x;
  const int lane = tid & 63;
  const int w = tid >> 6;
  const int m0 = blockIdx.x * 64 + w * 16;
  const int lr = lane & 15;
  const int quad = lane >> 4;
  const int koff = quad * 8;

  const ushort* vb[3] = {x, y1, y2};
  short8 a[12];
#pragma unroll
  for (int v = 0; v < 3; ++v)
#pragma unroll
    for (int h = 0; h < 4; ++h)
      a[v * 4 + h] = *(const short8*)(vb[v] + (size_t)(m0 + lr) * 128 + h * 32 + koff);

  const ushort* bru = Bru + (size_t)lane * 8;
  const ushort* bcin = Bcin + (size_t)lane * 8;

  floatx4 aru[8], ac[4];
#pragma unroll
  for (int nt = 0; nt < 8; ++nt) aru[nt] = {0.f, 0.f, 0.f, 0.f};
#pragma unroll
  for (int nt = 0; nt < 4; ++nt) ac[nt] = {0.f, 0.f, 0.f, 0.f};

  short8 bc[8];
#pragma unroll
  for (int nt = 0; nt < 8; ++nt) bc[nt] = *(const short8*)(bru + (size_t)nt * 512);

#pragma unroll
  for (int kt = 0; kt < 12; ++kt) {
    short8 bn[8];
    if (kt < 11) {
#pragma unroll
      for (int nt = 0; nt < 8; ++nt)
        bn[nt] = *(const short8*)(bru + (size_t)((kt + 1) * 8 + nt) * 512);
    }
#pragma unroll
    for (int nt = 0; nt < 8; ++nt)
      aru[nt] = __builtin_amdgcn_mfma_f32_16x16x32_bf16(a[kt], bc[nt], aru[nt], 0, 0, 0);
    const int h = kt & 3;
    if (h < 2) {
      const int ktc = (kt >> 2) * 2 + h;
#pragma unroll
      for (int nt = 0; nt < 4; ++nt) {
        short8 b2 = *(const short8*)(bcin + (size_t)(ktc * 4 + nt) * 512);
        ac[nt] = __builtin_amdgcn_mfma_f32_16x16x32_bf16(a[kt], b2, ac[nt], 0, 0, 0);
      }
    }
    if (kt < 11) {
#pragma unroll
      for (int nt = 0; nt < 8; ++nt) bc[nt] = bn[nt];
    }
  }

#pragma unroll
  for (int nt = 0; nt < 8; ++nt) {
    int col = nt * 16 + lr;
    float bv = bias[col];
#pragma unroll
    for (int i = 0; i < 4; ++i) {
      int m = m0 + quad * 4 + i;
      float s = 1.f / (1.f + expf(-(aru[nt][i] + bv)));
      if (nt < 4) {
        rh0[(size_t)m * 64 + col] = f2bf(s * hx[(size_t)m * 64 + col]);
      } else {
        u[(size_t)m * 64 + (col - 64)] = f2bf(s);
      }
    }
  }
#pragma unroll
  for (int nt = 0; nt < 4; ++nt) {
    int col = nt * 16 + lr;
#pragma unroll
    for (int i = 0; i < 4; ++i) {
      int m = m0 + quad * 4 + i;
      cp[(size_t)m * 64 + col] = f2bf(ac[nt][i]);
    }
  }
}

// ---------------- GEMM2: c-rh (K=192 over rh0/1/2) + cp + GRU output --------------

__global__ __launch_bounds__(256) void k_gemm2(
    const ushort* __restrict__ rh0, const ushort* __restrict__ rh1,
    const ushort* __restrict__ rh2, const ushort* __restrict__ Bc2,
    const float* __restrict__ bias, const ushort* __restrict__ cp,
    const ushort* __restrict__ uu, const float* __restrict__ hx,
    float* __restrict__ out) {
  const int tid = threadIdx.x;
  const int lane = tid & 63;
  const int w = tid >> 6;
  const int m0 = blockIdx.x * 64 + w * 16;
  const int lr = lane & 15;
  const int quad = lane >> 4;
  const int koff = quad * 8;

  const ushort* vb[3] = {rh0, rh1, rh2};
  short8 a[6];
#pragma unroll
  for (int v = 0; v < 3; ++v)
#pragma unroll
    for (int h = 0; h < 2; ++h)
      a[v * 2 + h] = *(const short8*)(vb[v] + (size_t)(m0 + lr) * 64 + h * 32 + koff);

  float cpv[16], uv[16], hxv[16];
#pragma unroll
  for (int nt = 0; nt < 4; ++nt)
#pragma unroll
    for (int i = 0; i < 4; ++i) {
      size_t idx = (size_t)(m0 + quad * 4 + i) * 64 + nt * 16 + lr;
      cpv[nt * 4 + i] = bf2f(cp[idx]);
      uv[nt * 4 + i] = bf2f(uu[idx]);
      hxv[nt * 4 + i] = hx[idx];
    }

  const ushort* bp = Bc2 + (size_t)lane * 8;
  floatx4 acc[4];
#pragma unroll
  for (int nt = 0; nt < 4; ++nt) acc[nt] = {0.f, 0.f, 0.f, 0.f};

  short8 bc[4];
#pragma unroll
  for (int nt = 0; nt < 4; ++nt) bc[nt] = *(const short8*)(bp + (size_t)nt * 512);

#pragma unroll
  for (int kt = 0; kt < 6; ++kt) {
    short8 bn[4];
    if (kt < 5) {
#pragma unroll
      for (int nt = 0; nt < 4; ++nt)
        bn[nt] = *(const short8*)(bp + (size_t)((kt + 1) * 4 + nt) * 512);
    }
#pragma unroll
    for (int nt = 0; nt < 4; ++nt)
      acc[nt] = __builtin_amdgcn_mfma_f32_16x16x32_bf16(a[kt], bc[nt], acc[nt], 0, 0, 0);
    if (kt < 5) {
#pragma unroll
      for (int nt = 0; nt < 4; ++nt) bc[nt] = bn[nt];
    }
  }

#pragma unroll
  for (int nt = 0; nt < 4; ++nt) {
    int col = nt * 16 + lr;
    float bv = bias[col];
#pragma unroll
    for (int i = 0; i < 4; ++i) {
      int m = m0 + quad * 4 + i;
      int j = nt * 4 + i;
      float c = tanhf(acc[nt][i] + cpv[j] + bv);
      out[(size_t)m * 64 + col] = uv[j] * hxv[j] + (1.f - uv[j]) * c;
    }
  }
}

// ---------------- launch ----------------

extern "C" void kernel_launch(void* const* d_in, const int* in_sizes, int n_in,
                              void* d_out, int out_size, void* d_ws, size_t ws_size,
                              hipStream_t stream) {
  const float* d_inputs = (const float*)d_in[0];
  const float* d_hx     = (const float*)d_in[1];
  const int*   d_sidx   = (const int*)d_in[2];
  const float* d_ker    = (const float*)d_in[3];
  const float* d_Wru    = (const float*)d_in[4];
  const float* d_bru    = (const float*)d_in[5];
  const float* d_Wc     = (const float*)d_in[6];
  const float* d_bc     = (const float*)d_in[7];
  float* out = (float*)d_out;
  const int* src = d_sidx;
  const int* dst = d_sidx + EE;

  // workspace layout (16B-aligned chunks); all tensors (B,N,C)
  ushort* x     = (ushort*)d_ws;                    // MM*128 [in|hx]
  ushort* y1    = x + (size_t)MM * 128;             // A [in|hx]
  ushort* y2    = y1 + (size_t)MM * 128;            // A^2 [in|hx]
  ushort* rh0   = y2 + (size_t)MM * 128;            // MM*64 r*hx
  ushort* rh1   = rh0 + (size_t)MM * 64;
  ushort* rh2   = rh1 + (size_t)MM * 64;
  ushort* u     = rh2 + (size_t)MM * 64;            // MM*64 bf16 u gate
  ushort* cp    = u + (size_t)MM * 64;              // MM*64 bf16 c-in-partial
  ushort* Bru   = cp + (size_t)MM * 64;             // packed 12*8*64*8
  ushort* Bcin  = Bru + 12 * 8 * 64 * 8;            // packed 6*4*64*8
  ushort* Bc2   = Bcin + 6 * 4 * 64 * 8;            // packed 6*4*64*8
  uint2*  edges = (uint2*)(Bc2 + 6 * 4 * 64 * 8);   // NB*SLOTS
  int*    cnt   = (int*)(edges + (size_t)NB * SLOTS);

  // cnt zero + fused {edge fill, build_xru, fragment-major W pack}
  hipMemsetAsync(cnt, 0, NB * sizeof(int), stream);
  k_misc<<<3161, 256, 0, stream>>>(src, dst, d_ker, cnt, edges,
                                   d_inputs, d_hx, x, d_Wru, d_Wc,
                                   Bru, Bcin, Bc2);

  // conv 1: [in|hx] -> prop x2 (128ch) -> gemm1 (ru gates + fused c-in-partial)
  k_prop128<<<10000, 256, 0, stream>>>(x, y1, cnt, edges);
  k_prop128<<<10000, 256, 0, stream>>>(y1, y2, cnt, edges);
  k_gemm1<<<625, 256, 0, stream>>>(x, y1, y2, Bru, Bcin, d_bru, d_hx,
                                   rh0, u, cp);

  // conv 2: propagate r*hx (64ch) x2 -> gemm2 (K=192 + cp + GRU output)
  k_prop64<<<10000, 256, 0, stream>>>(rh0, rh1, cnt, edges);
  k_prop64<<<10000, 256, 0, stream>>>(rh1, rh2, cnt, edges);
  k_gemm2<<<625, 256, 0, stream>>>(rh0, rh1, rh2, Bc2, d_bc, cp, u, d_hx, out);
}